// Round 1
// 493.451 us; speedup vs baseline: 1.0577x; 1.0577x over previous
//
#include <hip/hip_runtime.h>

// HMM forward: B=64, T=512, S=35, D=2496.
// emis: bf16 MFMA GEMM, NO LDS / NO BARRIERS — direct global->register
//       fragment loads, 6-chunk-deep A double-buffer, 1-chunk B double-buffer.
//       A-pack via v_cvt_pk_bf16_f32 (1 instr / 2 elems, RNE).
// forward: linear-space recursion p' = E_t (A p), DPP reductions.
//       Group-level (8-step) stabilizer Kg (one wmax per group, E precomputed),
//       wave_shr:1 DPP rotations (+readlane wrap fixes) instead of ds_bpermute.
//
// SESSION HYPOTHESIS (r0): dur_us ~= 2x200us harness poison-fills (in-graph,
// 1.31GB each) + ~120us of our kernels. Our floor: emis ~52us (327MB @6.3TB/s)
// + forward ~12us + prep ~3us.

#define ROWS 32768   // B*T
#define KD   2496
#define NS   35
#define SPAD 48
#define ES   40      // emis row stride (floats)
#define TT   512

typedef short v8s __attribute__((ext_vector_type(8)));
typedef float v4f __attribute__((ext_vector_type(4)));

__device__ __forceinline__ unsigned short f2bf(float f) {
    unsigned u = __builtin_bit_cast(unsigned, f);
    u += 0x7fffu + ((u >> 16) & 1u);   // RNE
    return (unsigned short)(u >> 16);
}

// ---- DPP cross-lane ops (VALU-latency, no LDS pipe) ----
template <int CTRL, int RM>
__device__ __forceinline__ float dppf(float oldv, float v) {
    return __builtin_bit_cast(float, __builtin_amdgcn_update_dpp(
        __builtin_bit_cast(int, oldv), __builtin_bit_cast(int, v),
        CTRL, RM, 0xf, false));
}

__device__ __forceinline__ float wsum63(float v) {
    v += dppf<0x111, 0xf>(0.f, v);   // row_shr:1
    v += dppf<0x112, 0xf>(0.f, v);   // row_shr:2
    v += dppf<0x114, 0xf>(0.f, v);   // row_shr:4
    v += dppf<0x118, 0xf>(0.f, v);   // row_shr:8
    v += dppf<0x142, 0xa>(0.f, v);   // row_bcast:15
    v += dppf<0x143, 0xc>(0.f, v);   // row_bcast:31
    return __builtin_bit_cast(float,
        __builtin_amdgcn_readlane(__builtin_bit_cast(int, v), 63));
}

__device__ __forceinline__ float wmax63(float v) {
    const float NI = -3.0e38f;
    v = fmaxf(v, dppf<0x111, 0xf>(NI, v));
    v = fmaxf(v, dppf<0x112, 0xf>(NI, v));
    v = fmaxf(v, dppf<0x114, 0xf>(NI, v));
    v = fmaxf(v, dppf<0x118, 0xf>(NI, v));
    v = fmaxf(v, dppf<0x142, 0xa>(NI, v));
    v = fmaxf(v, dppf<0x143, 0xc>(NI, v));
    return __builtin_bit_cast(float,
        __builtin_amdgcn_readlane(__builtin_bit_cast(int, v), 63));
}

__device__ __forceinline__ float rlane(float v, int l) {
    return __builtin_bit_cast(float,
        __builtin_amdgcn_readlane(__builtin_bit_cast(int, v), l));
}

// wave_shr:1 — lane i gets lane i-1 (lane 0 keeps old = v). gfx9-family DPP.
__device__ __forceinline__ float shr1(float v) {
    return dppf<0x138, 0xf>(v, v);
}

// v_cvt_pk_bf16_f32: D[15:0]=bf16(lo), D[31:16]=bf16(hi), RNE.
__device__ __forceinline__ int cvtpk(float lo, float hi) {
    int r;
    asm("v_cvt_pk_bf16_f32 %0, %1, %2" : "=v"(r) : "v"(lo), "v"(hi));
    return r;
}

// ---- Prep: bf16-convert obs_matrix (zero-pad to 48 states) + m_sq ----
__global__ __launch_bounds__(256) void prep_kernel(
        const float* __restrict__ m, unsigned short* __restrict__ mb,
        float* __restrict__ msq) {
    int s = blockIdx.x;
    int tid = threadIdx.x;
    float part = 0.f;
    for (int k = tid; k < KD; k += 256) {
        float v = (s < NS) ? m[s * KD + k] : 0.f;
        mb[s * KD + k] = f2bf(v);
        part += v * v;
    }
    __shared__ float red[256];
    red[tid] = part;
    __syncthreads();
    for (int off = 128; off > 0; off >>= 1) {
        if (tid < off) red[tid] += red[tid + off];
        __syncthreads();
    }
    if (tid == 0) msq[s] = red[0];
}

// ---- Emission GEMM, barrier-free. Wave = 16 rows x 48 states, K streamed ----
__global__ __launch_bounds__(256) void emis_kernel(
        const float* __restrict__ x, const unsigned short* __restrict__ mb,
        const float* __restrict__ msq, float* __restrict__ emis) {
    const int tid = threadIdx.x;
    const int lane = tid & 63, w = tid >> 6;
    const int fm = lane & 15, q = lane >> 4;
    const int row0 = blockIdx.x * 64 + w * 16;          // this wave's row tile
    const float* xr = x + (long)(row0 + fm) * KD + q * 8;     // lane A stream
    const unsigned short* mb0 = mb + (long)fm * KD + q * 8;   // lane B stream

    v4f acc[3] = {};
    float sq = 0.f;

    float4 cur[6][2], nxt[6][2];
#pragma unroll
    for (int i = 0; i < 6; ++i) {
        cur[i][0] = *(const float4*)&xr[i * 32];
        cur[i][1] = *(const float4*)&xr[i * 32 + 4];
    }
    v8s bc[3], bn[3];
#pragma unroll
    for (int nt = 0; nt < 3; ++nt)
        bc[nt] = *(const v8s*)&mb0[nt * 16 * KD];

    for (int g = 0; g < 13; ++g) {                      // 13 groups x 6 chunks
        const int kbase = g * 192;
        if (g + 1 < 13) {
            const float* xn = xr + kbase + 192;
#pragma unroll
            for (int i = 0; i < 6; ++i) {
                nxt[i][0] = *(const float4*)&xn[i * 32];
                nxt[i][1] = *(const float4*)&xn[i * 32 + 4];
            }
        }
#pragma unroll
        for (int i = 0; i < 6; ++i) {
            const int knext = kbase + (i + 1) * 32;     // B double-buffer
            if (knext < KD) {
#pragma unroll
                for (int nt = 0; nt < 3; ++nt)
                    bn[nt] = *(const v8s*)&mb0[nt * 16 * KD + knext];
            }
            const float4 v0 = cur[i][0], v1 = cur[i][1];
            sq += v0.x * v0.x + v0.y * v0.y + v0.z * v0.z + v0.w * v0.w
                + v1.x * v1.x + v1.y * v1.y + v1.z * v1.z + v1.w * v1.w;
            union { int i4[4]; v8s v; } au;
            au.i4[0] = cvtpk(v0.x, v0.y);
            au.i4[1] = cvtpk(v0.z, v0.w);
            au.i4[2] = cvtpk(v1.x, v1.y);
            au.i4[3] = cvtpk(v1.z, v1.w);
            const v8s a = au.v;
#pragma unroll
            for (int nt = 0; nt < 3; ++nt)
                acc[nt] = __builtin_amdgcn_mfma_f32_16x16x32_bf16(a, bc[nt], acc[nt], 0, 0, 0);
#pragma unroll
            for (int nt = 0; nt < 3; ++nt) bc[nt] = bn[nt];
        }
#pragma unroll
        for (int i = 0; i < 6; ++i) {
            cur[i][0] = nxt[i][0];
            cur[i][1] = nxt[i][1];
        }
    }

    // |x_row|^2: lane holds partial over k = q*8 .. ; reduce across q-groups
    float s2 = sq + __shfl_xor(sq, 16, 64);
    s2 += __shfl_xor(s2, 32, 64);        // lane (fm,q): full |x_{row0+fm}|^2
    float xs[4];
#pragma unroll
    for (int rg = 0; rg < 4; ++rg)
        xs[rg] = __shfl(s2, q * 4 + rg, 64);   // xsq of output row q*4+rg

    // D layout: col = lane&15 -> state, row = q*4+reg -> x-row
#pragma unroll
    for (int nt = 0; nt < 3; ++nt) {
        const int st = nt * 16 + fm;
        if (st < NS) {
            const float ms = msq[st];
#pragma unroll
            for (int rg = 0; rg < 4; ++rg) {
                emis[(long)(row0 + q * 4 + rg) * ES + st] =
                    (xs[rg] + ms - 2.f * acc[nt][rg]) * (-1.f / 500.f);
            }
        }
    }
}

// ---- Forward recursion, linear space, 8-deep e-prefetch, group stabilizer ----
__global__ __launch_bounds__(64) void forward_kernel(
        const float* __restrict__ emis, float* __restrict__ out) {
    const int b = blockIdx.x;
    const int j = threadIdx.x;
    const bool act = j < NS;
    const bool is0 = (j == 0), is1 = (j == 1);
    const int jc = act ? j : NS - 1;
    const float LOG2E = 1.4426950408889634f, LN2 = 0.6931471805599453f;
    const float c0 = 0.1f, c1 = 0.8f, c2 = 0.08f, cb = 0.02f / 35.f;
    const float NI = -3.0e38f;

    const float* ebj = emis + (long)b * TT * ES + jc;

    const float e0 = ebj[0];
    const float a0 = (act ? e0 : NI) + ((j == 0) ? 10.f : -10.f);
    float C = wmax63(act ? a0 : NI);
    float p = act ? __builtin_amdgcn_exp2f((a0 - C) * LOG2E) : 0.f;

    float cur[8], nxt[8];
#pragma unroll
    for (int i = 0; i < 8; ++i) cur[i] = ebj[(1 + i) * ES];   // t = 1..8

    for (int g = 0; g < 63; ++g) {
        const int tb = 9 + 8 * g;
#pragma unroll
        for (int i = 0; i < 8; ++i) {
            const int t = tb + i;
            nxt[i] = ebj[(t < TT ? t : TT - 1) * ES];
        }
        // Group stabilizer: one wave-max per 8 steps, fully off the p-chain.
        float mx8 = cur[0];
#pragma unroll
        for (int i = 1; i < 8; ++i) mx8 = fmaxf(mx8, cur[i]);
        const float Kg = wmax63(act ? mx8 : NI);
        float E[8], Eb[8];
#pragma unroll
        for (int i = 0; i < 8; ++i) {
            E[i]  = act ? __builtin_amdgcn_exp2f((cur[i] - Kg) * LOG2E) : 0.f;
            Eb[i] = E[i] * cb;
        }
        float S = 1.f;
#pragma unroll
        for (int i = 0; i < 8; ++i) {
            // rotations (VALU DPP, hidden under wsum chain)
            const float r1 = shr1(p);
            const float r2 = shr1(r1);
            const float p34 = rlane(p, 34), p33 = rlane(p, 33);
            const float pm1 = is0 ? p34 : r1;
            const float pm2 = is0 ? p33 : (is1 ? p34 : r2);
            S = wsum63(p);                                    // chain-dominant
            const float wv = E[i] * fmaf(c1, pm1, fmaf(c2, pm2, c0 * p));
            p = fmaf(Eb[i], S, wv);
        }
        p *= __builtin_amdgcn_rcpf(S);        // bookkeeping renorm (exact-tracked)
        C += 8.f * Kg + LN2 * __builtin_amdgcn_logf(S);
#pragma unroll
        for (int i = 0; i < 8; ++i) cur[i] = nxt[i];
    }
    // tail: t = 505..511 (7 steps)
    float mx7 = cur[0];
#pragma unroll
    for (int i = 1; i < 7; ++i) mx7 = fmaxf(mx7, cur[i]);
    const float Kt = wmax63(act ? mx7 : NI);
#pragma unroll
    for (int i = 0; i < 7; ++i) {
        const float E  = act ? __builtin_amdgcn_exp2f((cur[i] - Kt) * LOG2E) : 0.f;
        const float Eb = E * cb;
        const float r1 = shr1(p);
        const float r2 = shr1(r1);
        const float p34 = rlane(p, 34), p33 = rlane(p, 33);
        const float pm1 = is0 ? p34 : r1;
        const float pm2 = is0 ? p33 : (is1 ? p34 : r2);
        const float S = wsum63(p);
        const float wv = E * fmaf(c1, pm1, fmaf(c2, pm2, c0 * p));
        p = fmaf(Eb, S, wv);
    }
    C += 7.f * Kt;
    const float Sf = wsum63(p);
    if (j == 0) out[b] = C + LN2 * __builtin_amdgcn_logf(Sf);
}

extern "C" void kernel_launch(void* const* d_in, const int* in_sizes, int n_in,
                              void* d_out, int out_size, void* d_ws, size_t ws_size,
                              hipStream_t stream) {
    const float* obs  = (const float*)d_in[0];
    const float* obsm = (const float*)d_in[1];
    float* out = (float*)d_out;

    char* ws = (char*)d_ws;
    float* emis = (float*)ws;                               // 32768*40*4 = 5,242,880 B
    unsigned short* mb = (unsigned short*)(ws + 5242880);   // 48*2496*2  =   239,616 B
    float* msq = (float*)(ws + 5482496);                    // 48*4

    prep_kernel<<<SPAD, 256, 0, stream>>>(obsm, mb, msq);
    emis_kernel<<<ROWS / 64, 256, 0, stream>>>(obs, mb, msq, emis);
    forward_kernel<<<64, 64, 0, stream>>>(emis, out);
}

// Round 2
// 491.143 us; speedup vs baseline: 1.0627x; 1.0047x over previous
//
#include <hip/hip_runtime.h>

// HMM forward: B=64, T=512, S=35, D=2496.
// emis: bf16 MFMA GEMM, NO LDS / NO BARRIERS — direct global->register
//       fragment loads, 3-buffer 2-group-deep A prefetch (384 B/wave in
//       flight; Little's law fix for latency-limited HBM stream),
//       1-chunk B double-buffer, A-pack via v_cvt_pk_bf16_f32.
// forward: linear-space recursion p' = E_t (A p), DPP reductions,
//       group-level (8-step) stabilizer, wave_shr:1 DPP rotations.
//
// SESSION LOG:
// r0: 522 us. Theory: ~394us = harness poison-fills (in-graph), ours ~120us.
// r1: 493.5 us (group stabilizer + DPP rotate + cvt_pk). Fill theory held.
//     Ours ~99us: emis ~76 vs 52 floor -> latency-limited (1.5 KB/CU in
//     flight vs ~6-9 KB needed). This round: 2-group-deep prefetch.

#define ROWS 32768   // B*T
#define KD   2496
#define NS   35
#define SPAD 48
#define ES   40      // emis row stride (floats)
#define TT   512

typedef short v8s __attribute__((ext_vector_type(8)));
typedef float v4f __attribute__((ext_vector_type(4)));

__device__ __forceinline__ unsigned short f2bf(float f) {
    unsigned u = __builtin_bit_cast(unsigned, f);
    u += 0x7fffu + ((u >> 16) & 1u);   // RNE
    return (unsigned short)(u >> 16);
}

// ---- DPP cross-lane ops (VALU-latency, no LDS pipe) ----
template <int CTRL, int RM>
__device__ __forceinline__ float dppf(float oldv, float v) {
    return __builtin_bit_cast(float, __builtin_amdgcn_update_dpp(
        __builtin_bit_cast(int, oldv), __builtin_bit_cast(int, v),
        CTRL, RM, 0xf, false));
}

__device__ __forceinline__ float wsum63(float v) {
    v += dppf<0x111, 0xf>(0.f, v);   // row_shr:1
    v += dppf<0x112, 0xf>(0.f, v);   // row_shr:2
    v += dppf<0x114, 0xf>(0.f, v);   // row_shr:4
    v += dppf<0x118, 0xf>(0.f, v);   // row_shr:8
    v += dppf<0x142, 0xa>(0.f, v);   // row_bcast:15
    v += dppf<0x143, 0xc>(0.f, v);   // row_bcast:31
    return __builtin_bit_cast(float,
        __builtin_amdgcn_readlane(__builtin_bit_cast(int, v), 63));
}

__device__ __forceinline__ float wmax63(float v) {
    const float NI = -3.0e38f;
    v = fmaxf(v, dppf<0x111, 0xf>(NI, v));
    v = fmaxf(v, dppf<0x112, 0xf>(NI, v));
    v = fmaxf(v, dppf<0x114, 0xf>(NI, v));
    v = fmaxf(v, dppf<0x118, 0xf>(NI, v));
    v = fmaxf(v, dppf<0x142, 0xa>(NI, v));
    v = fmaxf(v, dppf<0x143, 0xc>(NI, v));
    return __builtin_bit_cast(float,
        __builtin_amdgcn_readlane(__builtin_bit_cast(int, v), 63));
}

__device__ __forceinline__ float rlane(float v, int l) {
    return __builtin_bit_cast(float,
        __builtin_amdgcn_readlane(__builtin_bit_cast(int, v), l));
}

// wave_shr:1 — lane i gets lane i-1 (lane 0 keeps old = v). gfx9-family DPP.
__device__ __forceinline__ float shr1(float v) {
    return dppf<0x138, 0xf>(v, v);
}

// v_cvt_pk_bf16_f32: D[15:0]=bf16(lo), D[31:16]=bf16(hi), RNE.
__device__ __forceinline__ int cvtpk(float lo, float hi) {
    int r;
    asm("v_cvt_pk_bf16_f32 %0, %1, %2" : "=v"(r) : "v"(lo), "v"(hi));
    return r;
}

// ---- Prep: bf16-convert obs_matrix (zero-pad to 48 states) + m_sq ----
__global__ __launch_bounds__(256) void prep_kernel(
        const float* __restrict__ m, unsigned short* __restrict__ mb,
        float* __restrict__ msq) {
    int s = blockIdx.x;
    int tid = threadIdx.x;
    float part = 0.f;
    for (int k = tid; k < KD; k += 256) {
        float v = (s < NS) ? m[s * KD + k] : 0.f;
        mb[s * KD + k] = f2bf(v);
        part += v * v;
    }
    __shared__ float red[256];
    red[tid] = part;
    __syncthreads();
    for (int off = 128; off > 0; off >>= 1) {
        if (tid < off) red[tid] += red[tid + off];
        __syncthreads();
    }
    if (tid == 0) msq[s] = red[0];
}

// ---- emis helpers: static-named buffers, fully inlined ----
__device__ __forceinline__ void loadg(float4 (&dst)[6][2], const float* xr, int g) {
    const float* xg = xr + g * 192;
#pragma unroll
    for (int i = 0; i < 6; ++i) {
        dst[i][0] = *(const float4*)&xg[i * 32];
        dst[i][1] = *(const float4*)&xg[i * 32 + 4];
    }
}

__device__ __forceinline__ void compg(const float4 (&cur)[6][2], int g,
        v4f (&acc)[3], float& sq, v8s (&bc)[3], v8s (&bn)[3],
        const unsigned short* mb0) {
    const int kbase = g * 192;
#pragma unroll
    for (int i = 0; i < 6; ++i) {
        const int knext = kbase + (i + 1) * 32;     // B double-buffer
        if (knext < KD) {
#pragma unroll
            for (int nt = 0; nt < 3; ++nt)
                bn[nt] = *(const v8s*)&mb0[nt * 16 * KD + knext];
        }
        const float4 v0 = cur[i][0], v1 = cur[i][1];
        sq += v0.x * v0.x + v0.y * v0.y + v0.z * v0.z + v0.w * v0.w
            + v1.x * v1.x + v1.y * v1.y + v1.z * v1.z + v1.w * v1.w;
        union { int i4[4]; v8s v; } au;
        au.i4[0] = cvtpk(v0.x, v0.y);
        au.i4[1] = cvtpk(v0.z, v0.w);
        au.i4[2] = cvtpk(v1.x, v1.y);
        au.i4[3] = cvtpk(v1.z, v1.w);
#pragma unroll
        for (int nt = 0; nt < 3; ++nt)
            acc[nt] = __builtin_amdgcn_mfma_f32_16x16x32_bf16(au.v, bc[nt], acc[nt], 0, 0, 0);
#pragma unroll
        for (int nt = 0; nt < 3; ++nt) bc[nt] = bn[nt];
    }
}

// ---- Emission GEMM, barrier-free. Wave = 16 rows x 48 states, K streamed.
//      3 rotating A buffers (2 groups in flight ahead of compute). ----
__global__ __launch_bounds__(256, 2) void emis_kernel(
        const float* __restrict__ x, const unsigned short* __restrict__ mb,
        const float* __restrict__ msq, float* __restrict__ emis) {
    const int tid = threadIdx.x;
    const int lane = tid & 63, w = tid >> 6;
    const int fm = lane & 15, q = lane >> 4;
    const int row0 = blockIdx.x * 64 + w * 16;          // this wave's row tile
    const float* xr = x + (long)(row0 + fm) * KD + q * 8;     // lane A stream
    const unsigned short* mb0 = mb + (long)fm * KD + q * 8;   // lane B stream

    v4f acc[3] = {};
    float sq = 0.f;

    float4 bA[6][2], bB[6][2], bC[6][2];
    v8s bc[3], bn[3];

    loadg(bA, xr, 0);
    loadg(bB, xr, 1);
#pragma unroll
    for (int nt = 0; nt < 3; ++nt)
        bc[nt] = *(const v8s*)&mb0[nt * 16 * KD];

    // rotation: at step g compute buf[g%3], prefetch group g+2 into buf[(g+2)%3]
    loadg(bC, xr, 2);   compg(bA, 0,  acc, sq, bc, bn, mb0);
    loadg(bA, xr, 3);   compg(bB, 1,  acc, sq, bc, bn, mb0);
    loadg(bB, xr, 4);   compg(bC, 2,  acc, sq, bc, bn, mb0);
    loadg(bC, xr, 5);   compg(bA, 3,  acc, sq, bc, bn, mb0);
    loadg(bA, xr, 6);   compg(bB, 4,  acc, sq, bc, bn, mb0);
    loadg(bB, xr, 7);   compg(bC, 5,  acc, sq, bc, bn, mb0);
    loadg(bC, xr, 8);   compg(bA, 6,  acc, sq, bc, bn, mb0);
    loadg(bA, xr, 9);   compg(bB, 7,  acc, sq, bc, bn, mb0);
    loadg(bB, xr, 10);  compg(bC, 8,  acc, sq, bc, bn, mb0);
    loadg(bC, xr, 11);  compg(bA, 9,  acc, sq, bc, bn, mb0);
    loadg(bA, xr, 12);  compg(bB, 10, acc, sq, bc, bn, mb0);
    compg(bC, 11, acc, sq, bc, bn, mb0);
    compg(bA, 12, acc, sq, bc, bn, mb0);

    // |x_row|^2: lane holds partial over k = q*8 .. ; reduce across q-groups
    float s2 = sq + __shfl_xor(sq, 16, 64);
    s2 += __shfl_xor(s2, 32, 64);        // lane (fm,q): full |x_{row0+fm}|^2
    float xs[4];
#pragma unroll
    for (int rg = 0; rg < 4; ++rg)
        xs[rg] = __shfl(s2, q * 4 + rg, 64);   // xsq of output row q*4+rg

    // D layout: col = lane&15 -> state, row = q*4+reg -> x-row
#pragma unroll
    for (int nt = 0; nt < 3; ++nt) {
        const int st = nt * 16 + fm;
        if (st < NS) {
            const float ms = msq[st];
#pragma unroll
            for (int rg = 0; rg < 4; ++rg) {
                emis[(long)(row0 + q * 4 + rg) * ES + st] =
                    (xs[rg] + ms - 2.f * acc[nt][rg]) * (-1.f / 500.f);
            }
        }
    }
}

// ---- Forward recursion, linear space, 8-deep e-prefetch, group stabilizer ----
__global__ __launch_bounds__(64) void forward_kernel(
        const float* __restrict__ emis, float* __restrict__ out) {
    const int b = blockIdx.x;
    const int j = threadIdx.x;
    const bool act = j < NS;
    const bool is0 = (j == 0), is1 = (j == 1);
    const int jc = act ? j : NS - 1;
    const float LOG2E = 1.4426950408889634f, LN2 = 0.6931471805599453f;
    const float c0 = 0.1f, c1 = 0.8f, c2 = 0.08f, cb = 0.02f / 35.f;
    const float NI = -3.0e38f;

    const float* ebj = emis + (long)b * TT * ES + jc;

    const float e0 = ebj[0];
    const float a0 = (act ? e0 : NI) + ((j == 0) ? 10.f : -10.f);
    float C = wmax63(act ? a0 : NI);
    float p = act ? __builtin_amdgcn_exp2f((a0 - C) * LOG2E) : 0.f;

    float cur[8], nxt[8];
#pragma unroll
    for (int i = 0; i < 8; ++i) cur[i] = ebj[(1 + i) * ES];   // t = 1..8

    for (int g = 0; g < 63; ++g) {
        const int tb = 9 + 8 * g;
#pragma unroll
        for (int i = 0; i < 8; ++i) {
            const int t = tb + i;
            nxt[i] = ebj[(t < TT ? t : TT - 1) * ES];
        }
        // Group stabilizer: one wave-max per 8 steps, fully off the p-chain.
        float mx8 = cur[0];
#pragma unroll
        for (int i = 1; i < 8; ++i) mx8 = fmaxf(mx8, cur[i]);
        const float Kg = wmax63(act ? mx8 : NI);
        float E[8], Eb[8];
#pragma unroll
        for (int i = 0; i < 8; ++i) {
            E[i]  = act ? __builtin_amdgcn_exp2f((cur[i] - Kg) * LOG2E) : 0.f;
            Eb[i] = E[i] * cb;
        }
        float S = 1.f;
#pragma unroll
        for (int i = 0; i < 8; ++i) {
            // rotations (VALU DPP, hidden under wsum chain)
            const float r1 = shr1(p);
            const float r2 = shr1(r1);
            const float p34 = rlane(p, 34), p33 = rlane(p, 33);
            const float pm1 = is0 ? p34 : r1;
            const float pm2 = is0 ? p33 : (is1 ? p34 : r2);
            S = wsum63(p);                                    // chain-dominant
            const float wv = E[i] * fmaf(c1, pm1, fmaf(c2, pm2, c0 * p));
            p = fmaf(Eb[i], S, wv);
        }
        p *= __builtin_amdgcn_rcpf(S);        // bookkeeping renorm (exact-tracked)
        C += 8.f * Kg + LN2 * __builtin_amdgcn_logf(S);
#pragma unroll
        for (int i = 0; i < 8; ++i) cur[i] = nxt[i];
    }
    // tail: t = 505..511 (7 steps)
    float mx7 = cur[0];
#pragma unroll
    for (int i = 1; i < 7; ++i) mx7 = fmaxf(mx7, cur[i]);
    const float Kt = wmax63(act ? mx7 : NI);
#pragma unroll
    for (int i = 0; i < 7; ++i) {
        const float E  = act ? __builtin_amdgcn_exp2f((cur[i] - Kt) * LOG2E) : 0.f;
        const float Eb = E * cb;
        const float r1 = shr1(p);
        const float r2 = shr1(r1);
        const float p34 = rlane(p, 34), p33 = rlane(p, 33);
        const float pm1 = is0 ? p34 : r1;
        const float pm2 = is0 ? p33 : (is1 ? p34 : r2);
        const float S = wsum63(p);
        const float wv = E * fmaf(c1, pm1, fmaf(c2, pm2, c0 * p));
        p = fmaf(Eb, S, wv);
    }
    C += 7.f * Kt;
    const float Sf = wsum63(p);
    if (j == 0) out[b] = C + LN2 * __builtin_amdgcn_logf(Sf);
}

extern "C" void kernel_launch(void* const* d_in, const int* in_sizes, int n_in,
                              void* d_out, int out_size, void* d_ws, size_t ws_size,
                              hipStream_t stream) {
    const float* obs  = (const float*)d_in[0];
    const float* obsm = (const float*)d_in[1];
    float* out = (float*)d_out;

    char* ws = (char*)d_ws;
    float* emis = (float*)ws;                               // 32768*40*4 = 5,242,880 B
    unsigned short* mb = (unsigned short*)(ws + 5242880);   // 48*2496*2  =   239,616 B
    float* msq = (float*)(ws + 5482496);                    // 48*4

    prep_kernel<<<SPAD, 256, 0, stream>>>(obsm, mb, msq);
    emis_kernel<<<ROWS / 64, 256, 0, stream>>>(obs, mb, msq, emis);
    forward_kernel<<<64, 64, 0, stream>>>(emis, out);
}

// Round 3
// 486.249 us; speedup vs baseline: 1.0734x; 1.0101x over previous
//
#include <hip/hip_runtime.h>

// HMM forward: B=64, T=512, S=35, D=2496.
// emis: bf16 MFMA GEMM, NO LDS / NO BARRIERS. Unified chunk-granular FIFO
//       pipeline: each chunk's {2x A dwordx4, 3x B dwordx4} issued exactly
//       6 chunks ahead through 6 statically-named buffers -> all waits are
//       counted vmcnt(25), never a drain. (r2 post-mortem: per-chunk B loads
//       issued after far A-prefetch forced in-order vmcnt drains, collapsing
//       prefetch depth to ~1 group.)
// forward: linear-space recursion p' = E_t (A p), DPP reductions,
//       group-level (8-step) stabilizer, wave_shr:1 DPP rotations.
//       Issue(~440cy) and chain(~440cy) balanced -> structural floor, frozen.
//
// SESSION LOG:
// r0: 522 us. Theory: ~394us = harness poison-fills (in-graph), ours ~120us.
// r1: 493.5 us (group stabilizer + DPP rotate + cvt_pk). Fills confirmed.
// r2: 491.1 us. Deep A-prefetch null (-2.4us) -> diagnosed vmcnt in-order
//     drain via interleaved B loads. This round: chunk-FIFO, counted waits.
//     If null again: emis is at achievable-BW for strided 16-row streams.

#define ROWS 32768   // B*T
#define KD   2496
#define NS   35
#define SPAD 48
#define ES   40      // emis row stride (floats)
#define TT   512

typedef short v8s __attribute__((ext_vector_type(8)));
typedef float v4f __attribute__((ext_vector_type(4)));

__device__ __forceinline__ unsigned short f2bf(float f) {
    unsigned u = __builtin_bit_cast(unsigned, f);
    u += 0x7fffu + ((u >> 16) & 1u);   // RNE
    return (unsigned short)(u >> 16);
}

// ---- DPP cross-lane ops (VALU-latency, no LDS pipe) ----
template <int CTRL, int RM>
__device__ __forceinline__ float dppf(float oldv, float v) {
    return __builtin_bit_cast(float, __builtin_amdgcn_update_dpp(
        __builtin_bit_cast(int, oldv), __builtin_bit_cast(int, v),
        CTRL, RM, 0xf, false));
}

__device__ __forceinline__ float wsum63(float v) {
    v += dppf<0x111, 0xf>(0.f, v);   // row_shr:1
    v += dppf<0x112, 0xf>(0.f, v);   // row_shr:2
    v += dppf<0x114, 0xf>(0.f, v);   // row_shr:4
    v += dppf<0x118, 0xf>(0.f, v);   // row_shr:8
    v += dppf<0x142, 0xa>(0.f, v);   // row_bcast:15
    v += dppf<0x143, 0xc>(0.f, v);   // row_bcast:31
    return __builtin_bit_cast(float,
        __builtin_amdgcn_readlane(__builtin_bit_cast(int, v), 63));
}

__device__ __forceinline__ float wmax63(float v) {
    const float NI = -3.0e38f;
    v = fmaxf(v, dppf<0x111, 0xf>(NI, v));
    v = fmaxf(v, dppf<0x112, 0xf>(NI, v));
    v = fmaxf(v, dppf<0x114, 0xf>(NI, v));
    v = fmaxf(v, dppf<0x118, 0xf>(NI, v));
    v = fmaxf(v, dppf<0x142, 0xa>(NI, v));
    v = fmaxf(v, dppf<0x143, 0xc>(NI, v));
    return __builtin_bit_cast(float,
        __builtin_amdgcn_readlane(__builtin_bit_cast(int, v), 63));
}

__device__ __forceinline__ float rlane(float v, int l) {
    return __builtin_bit_cast(float,
        __builtin_amdgcn_readlane(__builtin_bit_cast(int, v), l));
}

// wave_shr:1 — lane i gets lane i-1 (lane 0 keeps old = v). gfx9-family DPP.
__device__ __forceinline__ float shr1(float v) {
    return dppf<0x138, 0xf>(v, v);
}

// v_cvt_pk_bf16_f32: D[15:0]=bf16(lo), D[31:16]=bf16(hi), RNE.
__device__ __forceinline__ int cvtpk(float lo, float hi) {
    int r;
    asm("v_cvt_pk_bf16_f32 %0, %1, %2" : "=v"(r) : "v"(lo), "v"(hi));
    return r;
}

// ---- Prep: bf16-convert obs_matrix (zero-pad to 48 states) + m_sq ----
__global__ __launch_bounds__(256) void prep_kernel(
        const float* __restrict__ m, unsigned short* __restrict__ mb,
        float* __restrict__ msq) {
    int s = blockIdx.x;
    int tid = threadIdx.x;
    float part = 0.f;
    for (int k = tid; k < KD; k += 256) {
        float v = (s < NS) ? m[s * KD + k] : 0.f;
        mb[s * KD + k] = f2bf(v);
        part += v * v;
    }
    __shared__ float red[256];
    red[tid] = part;
    __syncthreads();
    for (int off = 128; off > 0; off >>= 1) {
        if (tid < off) red[tid] += red[tid + off];
        __syncthreads();
    }
    if (tid == 0) msq[s] = red[0];
}

// ---- emis chunk pipeline: statically-named rotating buffers ----
struct Ch { float4 a0, a1; v8s b0, b1, b2; };

__device__ __forceinline__ void issue_ch(Ch& d, const float* xr,
        const unsigned short* mb0, int c) {
    const float* xa = xr + c * 32;
    d.a0 = *(const float4*)&xa[0];
    d.a1 = *(const float4*)&xa[4];
    const unsigned short* mc = mb0 + c * 32;
    d.b0 = *(const v8s*)&mc[0];
    d.b1 = *(const v8s*)&mc[16 * KD];
    d.b2 = *(const v8s*)&mc[32 * KD];
}

__device__ __forceinline__ void comp_ch(const Ch& ch, v4f (&acc)[3], float& sq) {
    const float4 v0 = ch.a0, v1 = ch.a1;
    sq += v0.x * v0.x + v0.y * v0.y + v0.z * v0.z + v0.w * v0.w
        + v1.x * v1.x + v1.y * v1.y + v1.z * v1.z + v1.w * v1.w;
    union { int i4[4]; v8s v; } au;
    au.i4[0] = cvtpk(v0.x, v0.y);
    au.i4[1] = cvtpk(v0.z, v0.w);
    au.i4[2] = cvtpk(v1.x, v1.y);
    au.i4[3] = cvtpk(v1.z, v1.w);
    acc[0] = __builtin_amdgcn_mfma_f32_16x16x32_bf16(au.v, ch.b0, acc[0], 0, 0, 0);
    acc[1] = __builtin_amdgcn_mfma_f32_16x16x32_bf16(au.v, ch.b1, acc[1], 0, 0, 0);
    acc[2] = __builtin_amdgcn_mfma_f32_16x16x32_bf16(au.v, ch.b2, acc[2], 0, 0, 0);
}

// ---- Emission GEMM, barrier-free. Wave = 16 rows x 48 states.
//      78 K-chunks of 32; FIFO depth 6 chunks (30 loads in flight). ----
__global__ __launch_bounds__(256, 2) void emis_kernel(
        const float* __restrict__ x, const unsigned short* __restrict__ mb,
        const float* __restrict__ msq, float* __restrict__ emis) {
    const int tid = threadIdx.x;
    const int lane = tid & 63, w = tid >> 6;
    const int fm = lane & 15, q = lane >> 4;
    const int row0 = blockIdx.x * 64 + w * 16;          // this wave's row tile
    const float* xr = x + (long)(row0 + fm) * KD + q * 8;     // lane A stream
    const unsigned short* mb0 = mb + (long)fm * KD + q * 8;   // lane B stream

    v4f acc[3] = {};
    float sq = 0.f;

    Ch h0, h1, h2, h3, h4, h5;
    issue_ch(h0, xr, mb0, 0);
    issue_ch(h1, xr, mb0, 1);
    issue_ch(h2, xr, mb0, 2);
    issue_ch(h3, xr, mb0, 3);
    issue_ch(h4, xr, mb0, 4);
    issue_ch(h5, xr, mb0, 5);

    int kq = 6;
    for (int j = 0; j < 11; ++j) {       // computes chunks 0..65, issues 6..71
        comp_ch(h0, acc, sq); issue_ch(h0, xr, mb0, kq + 0);
        comp_ch(h1, acc, sq); issue_ch(h1, xr, mb0, kq + 1);
        comp_ch(h2, acc, sq); issue_ch(h2, xr, mb0, kq + 2);
        comp_ch(h3, acc, sq); issue_ch(h3, xr, mb0, kq + 3);
        comp_ch(h4, acc, sq); issue_ch(h4, xr, mb0, kq + 4);
        comp_ch(h5, acc, sq); issue_ch(h5, xr, mb0, kq + 5);
        kq += 6;
    }
    // computes 66..71, issues 72..77
    comp_ch(h0, acc, sq); issue_ch(h0, xr, mb0, 72);
    comp_ch(h1, acc, sq); issue_ch(h1, xr, mb0, 73);
    comp_ch(h2, acc, sq); issue_ch(h2, xr, mb0, 74);
    comp_ch(h3, acc, sq); issue_ch(h3, xr, mb0, 75);
    comp_ch(h4, acc, sq); issue_ch(h4, xr, mb0, 76);
    comp_ch(h5, acc, sq); issue_ch(h5, xr, mb0, 77);
    // computes 72..77
    comp_ch(h0, acc, sq);
    comp_ch(h1, acc, sq);
    comp_ch(h2, acc, sq);
    comp_ch(h3, acc, sq);
    comp_ch(h4, acc, sq);
    comp_ch(h5, acc, sq);

    // |x_row|^2: lane holds partial over k = q*8 .. ; reduce across q-groups
    float s2 = sq + __shfl_xor(sq, 16, 64);
    s2 += __shfl_xor(s2, 32, 64);        // lane (fm,q): full |x_{row0+fm}|^2
    float xs[4];
#pragma unroll
    for (int rg = 0; rg < 4; ++rg)
        xs[rg] = __shfl(s2, q * 4 + rg, 64);   // xsq of output row q*4+rg

    // D layout: col = lane&15 -> state, row = q*4+reg -> x-row
#pragma unroll
    for (int nt = 0; nt < 3; ++nt) {
        const int st = nt * 16 + fm;
        if (st < NS) {
            const float ms = msq[st];
#pragma unroll
            for (int rg = 0; rg < 4; ++rg) {
                emis[(long)(row0 + q * 4 + rg) * ES + st] =
                    (xs[rg] + ms - 2.f * acc[nt][rg]) * (-1.f / 500.f);
            }
        }
    }
}

// ---- Forward recursion, linear space, 8-deep e-prefetch, group stabilizer ----
__global__ __launch_bounds__(64) void forward_kernel(
        const float* __restrict__ emis, float* __restrict__ out) {
    const int b = blockIdx.x;
    const int j = threadIdx.x;
    const bool act = j < NS;
    const bool is0 = (j == 0), is1 = (j == 1);
    const int jc = act ? j : NS - 1;
    const float LOG2E = 1.4426950408889634f, LN2 = 0.6931471805599453f;
    const float c0 = 0.1f, c1 = 0.8f, c2 = 0.08f, cb = 0.02f / 35.f;
    const float NI = -3.0e38f;

    const float* ebj = emis + (long)b * TT * ES + jc;

    const float e0 = ebj[0];
    const float a0 = (act ? e0 : NI) + ((j == 0) ? 10.f : -10.f);
    float C = wmax63(act ? a0 : NI);
    float p = act ? __builtin_amdgcn_exp2f((a0 - C) * LOG2E) : 0.f;

    float cur[8], nxt[8];
#pragma unroll
    for (int i = 0; i < 8; ++i) cur[i] = ebj[(1 + i) * ES];   // t = 1..8

    for (int g = 0; g < 63; ++g) {
        const int tb = 9 + 8 * g;
#pragma unroll
        for (int i = 0; i < 8; ++i) {
            const int t = tb + i;
            nxt[i] = ebj[(t < TT ? t : TT - 1) * ES];
        }
        // Group stabilizer: one wave-max per 8 steps, fully off the p-chain.
        float mx8 = cur[0];
#pragma unroll
        for (int i = 1; i < 8; ++i) mx8 = fmaxf(mx8, cur[i]);
        const float Kg = wmax63(act ? mx8 : NI);
        float E[8], Eb[8];
#pragma unroll
        for (int i = 0; i < 8; ++i) {
            E[i]  = act ? __builtin_amdgcn_exp2f((cur[i] - Kg) * LOG2E) : 0.f;
            Eb[i] = E[i] * cb;
        }
        float S = 1.f;
#pragma unroll
        for (int i = 0; i < 8; ++i) {
            // rotations (VALU DPP, hidden under wsum chain)
            const float r1 = shr1(p);
            const float r2 = shr1(r1);
            const float p34 = rlane(p, 34), p33 = rlane(p, 33);
            const float pm1 = is0 ? p34 : r1;
            const float pm2 = is0 ? p33 : (is1 ? p34 : r2);
            S = wsum63(p);                                    // chain-dominant
            const float wv = E[i] * fmaf(c1, pm1, fmaf(c2, pm2, c0 * p));
            p = fmaf(Eb[i], S, wv);
        }
        p *= __builtin_amdgcn_rcpf(S);        // bookkeeping renorm (exact-tracked)
        C += 8.f * Kg + LN2 * __builtin_amdgcn_logf(S);
#pragma unroll
        for (int i = 0; i < 8; ++i) cur[i] = nxt[i];
    }
    // tail: t = 505..511 (7 steps)
    float mx7 = cur[0];
#pragma unroll
    for (int i = 1; i < 7; ++i) mx7 = fmaxf(mx7, cur[i]);
    const float Kt = wmax63(act ? mx7 : NI);
#pragma unroll
    for (int i = 0; i < 7; ++i) {
        const float E  = act ? __builtin_amdgcn_exp2f((cur[i] - Kt) * LOG2E) : 0.f;
        const float Eb = E * cb;
        const float r1 = shr1(p);
        const float r2 = shr1(r1);
        const float p34 = rlane(p, 34), p33 = rlane(p, 33);
        const float pm1 = is0 ? p34 : r1;
        const float pm2 = is0 ? p33 : (is1 ? p34 : r2);
        const float S = wsum63(p);
        const float wv = E * fmaf(c1, pm1, fmaf(c2, pm2, c0 * p));
        p = fmaf(Eb, S, wv);
    }
    C += 7.f * Kt;
    const float Sf = wsum63(p);
    if (j == 0) out[b] = C + LN2 * __builtin_amdgcn_logf(Sf);
}

extern "C" void kernel_launch(void* const* d_in, const int* in_sizes, int n_in,
                              void* d_out, int out_size, void* d_ws, size_t ws_size,
                              hipStream_t stream) {
    const float* obs  = (const float*)d_in[0];
    const float* obsm = (const float*)d_in[1];
    float* out = (float*)d_out;

    char* ws = (char*)d_ws;
    float* emis = (float*)ws;                               // 32768*40*4 = 5,242,880 B
    unsigned short* mb = (unsigned short*)(ws + 5242880);   // 48*2496*2  =   239,616 B
    float* msq = (float*)(ws + 5482496);                    // 48*4

    prep_kernel<<<SPAD, 256, 0, stream>>>(obsm, mb, msq);
    emis_kernel<<<ROWS / 64, 256, 0, stream>>>(obs, mb, msq, emis);
    forward_kernel<<<64, 64, 0, stream>>>(emis, out);
}